// Round 1
// baseline (1413.145 us; speedup 1.0000x reference)
//
#include <hip/hip_runtime.h>
#include <math.h>

#define NB_B 65536
#define NL   512
#define NP   96
#define NE   16
#define NEL  14
#define NF   256
#define TEMP_INV (1.0f/0.07f)
#define TAU  1e-5f
#define PI_D 3.14159265358979323846

// ---------------- workspace layout (bytes) ----------------
// 0       cnt[16]            (int)
// 64      flagcnt            (int)
// 128     flaglist[65536]    (int)
// 262272  Ssum[14*96]        (f32)   sum_l Wr[e,p,l]
// 267648  WgT[256*16]        (f32)   Wg^T * (1/TEMP)
// 284032  bgT[16]            (f32)   bg * (1/TEMP)
// 284096  twf[256]           (float2)  exp(-2pi i t/512) f32
// 286144  twd[512]           (double2) exp(-2pi i t/512) f64
// 294336  idxl[14*65536]     (int)
// 3964352 wl[14*65536]       (f32)
// total ~7.3 MB

__global__ __launch_bounds__(256) void k_prep(
    const float* __restrict__ Wg, const float* __restrict__ bg,
    const float* __restrict__ Wr,
    float* __restrict__ Ssum, float* __restrict__ WgT, float* __restrict__ bgT,
    float2* __restrict__ twf, double2* __restrict__ twd,
    int* __restrict__ cnt, int* __restrict__ flagcnt)
{
    int g = blockIdx.x * 256 + threadIdx.x;
    if (g < NEL * NP) {
        const float4* w = (const float4*)(Wr + (size_t)g * NL);
        float s = 0.f;
        for (int i = 0; i < NL / 4; i++) { float4 v = w[i]; s += v.x + v.y + v.z + v.w; }
        Ssum[g] = s;
    }
    if (g < NF * NE) {
        int f = g >> 4, e = g & 15;
        WgT[g] = Wg[e * NF + f] * TEMP_INV;
    }
    if (g < NF) {
        double a = -2.0 * PI_D * (double)g / 512.0;
        twf[g] = make_float2((float)cos(a), (float)sin(a));
    }
    if (g < 512) {
        double a = -2.0 * PI_D * (double)g / 512.0;
        twd[g] = make_double2(cos(a), sin(a));
    }
    if (g < NE) { bgT[g] = bg[g] * TEMP_INV; cnt[g] = 0; }
    if (g == 31) *flagcnt = 0;
}

// Per-row: register FFT (512pt, 8 regs/lane, 64 lanes), periodogram, gate,
// top-2, softmax, base output (const terms + trivial experts), bucket append.
__global__ __launch_bounds__(64) void k_gate(
    const float* __restrict__ x,
    const float* __restrict__ WgT, const float* __restrict__ bgT,
    const float2* __restrict__ twf,
    const float* __restrict__ Ssum, const float* __restrict__ br,
    float* __restrict__ out,
    int* __restrict__ cnt, int* __restrict__ idxl, float* __restrict__ wl,
    int* __restrict__ flaglist, int* __restrict__ flagcnt)
{
    __shared__ float2 s_tw[256];
    __shared__ float  s_I[288];   // padded index f + (f>>3) to break bank conflicts
    __shared__ float  s_g[16];
    const int b = blockIdx.x;
    const int l = threadIdx.x;
    s_tw[l] = twf[l]; s_tw[l + 64] = twf[l + 64];
    s_tw[l + 128] = twf[l + 128]; s_tw[l + 192] = twf[l + 192];

    const float* xp = x + (size_t)b * NL;
    float xr[8], xi[8];
#pragma unroll
    for (int k = 0; k < 8; k++) xr[k] = xp[k * 64 + l];   // element n = k*64 + l

    float sum = 0.f, sq = 0.f;
#pragma unroll
    for (int k = 0; k < 8; k++) { sum += xr[k]; sq += xr[k] * xr[k]; }
#pragma unroll
    for (int m = 1; m < 64; m <<= 1) { sum += __shfl_xor(sum, m); sq += __shfl_xor(sq, m); }
    const float mu = sum * (1.f / 512.f);
    const float var = sq * (1.f / 512.f) - mu * mu;
    const float sd = sqrtf(var + 1e-5f);
    const float last = __shfl(xr[7], 63);
#pragma unroll
    for (int k = 0; k < 8; k++) { xr[k] -= mu; xi[k] = 0.f; }
    __syncthreads();

    // ---- DIF FFT, natural in, bit-reversed out ----
    // stage 0: half=256, pairs (k,k+4), t = k*64+l
#pragma unroll
    for (int k = 0; k < 4; k++) {
        float2 w = s_tw[k * 64 + l];
        float ur = xr[k], ui = xi[k], vr = xr[k + 4], vi = xi[k + 4];
        xr[k] = ur + vr; xi[k] = ui + vi;
        float dr = ur - vr, di = ui - vi;
        xr[k + 4] = dr * w.x - di * w.y; xi[k + 4] = dr * w.y + di * w.x;
    }
    // stage 1: half=128, pairs (0,2),(1,3),(4,6),(5,7), t = ((k&1)*64+l)<<1
    {
        const int kk[4] = {0, 1, 4, 5};
#pragma unroll
        for (int g2 = 0; g2 < 4; g2++) {
            int k = kk[g2];
            float2 w = s_tw[((k & 1) * 64 + l) << 1];
            float ur = xr[k], ui = xi[k], vr = xr[k + 2], vi = xi[k + 2];
            xr[k] = ur + vr; xi[k] = ui + vi;
            float dr = ur - vr, di = ui - vi;
            xr[k + 2] = dr * w.x - di * w.y; xi[k + 2] = dr * w.y + di * w.x;
        }
    }
    // stage 2: half=64, pairs (k,k+1) k even, t = l<<2
    {
        float2 w = s_tw[l << 2];
#pragma unroll
        for (int k = 0; k < 8; k += 2) {
            float ur = xr[k], ui = xi[k], vr = xr[k + 1], vi = xi[k + 1];
            xr[k] = ur + vr; xi[k] = ui + vi;
            float dr = ur - vr, di = ui - vi;
            xr[k + 1] = dr * w.x - di * w.y; xi[k + 1] = dr * w.y + di * w.x;
        }
    }
    // stages 3..8: cross-lane via shfl_xor(half), half = 32,16,8,4,2,1
#pragma unroll
    for (int st = 3; st < 9; st++) {
        const int half = 256 >> st;
        const int tt = (l & (half - 1)) << st;
        float2 w = s_tw[tt];
        const bool up = (l & half) != 0;
        const float cc = up ? w.x : 1.f;
        const float ss = up ? w.y : 0.f;
#pragma unroll
        for (int k = 0; k < 8; k++) {
            float pr = __shfl_xor(xr[k], half);
            float pi = __shfl_xor(xi[k], half);
            float ar = up ? (pr - xr[k]) : (xr[k] + pr);
            float ai = up ? (pi - xi[k]) : (xi[k] + pi);
            xr[k] = ar * cc - ai * ss;
            xi[k] = ar * ss + ai * cc;
        }
    }

    // periodogram: even-l lanes hold bins f<256 (f = bitrev9(i))
    float psum = 0.f;
    if ((l & 1) == 0) {
#pragma unroll
        for (int k = 0; k < 8; k++) {
            unsigned i = (unsigned)(k * 64 + l);
            int f = (int)(__brev(i) >> 23);
            float I = xr[k] * xr[k] + xi[k] * xi[k];
            s_I[f + (f >> 3)] = I;
            psum += I;
        }
    }
#pragma unroll
    for (int m = 1; m < 64; m <<= 1) psum += __shfl_xor(psum, m);
    if (psum == 0.f) psum = 1.f;
    const float inv = 1.f / psum;
    __syncthreads();

    // gate: 16 experts x 4 lanes each, 64 bins per lane
    {
        int e = l >> 2, cq = l & 3;
        float acc = 0.f;
#pragma unroll 4
        for (int j = 0; j < 64; j++) {
            int f = cq * 64 + j;
            acc += s_I[f + (f >> 3)] * WgT[f * 16 + e];
        }
        acc += __shfl_xor(acc, 1);
        acc += __shfl_xor(acc, 2);
        if (cq == 0) s_g[e] = acc * inv + bgT[e];
    }
    __syncthreads();

    // top-2 (strict > keeps lowest index on ties, matching lax.top_k), track 3rd for flag
    float b0 = -1e30f, b1 = -1e30f, b2 = -1e30f; int i0 = 0, i1 = 0;
    for (int i = 0; i < 16; i++) {
        float v = s_g[i];
        if (v > b0) { b2 = b1; b1 = b0; i1 = i0; b0 = v; i0 = i; }
        else if (v > b1) { b2 = b1; b1 = v; i1 = i; }
        else if (v > b2) { b2 = v; }
    }
    if (b1 - b2 < TAU) {          // 2nd/3rd too close for f32 FFT: defer to f64 refine
        if (l == 0) { int pos = atomicAdd(flagcnt, 1); flaglist[pos] = b; }
        return;
    }
    float e1 = expf(b1 - b0);
    float w0 = 1.f / (1.f + e1), w1 = e1 * w0;

    float* op = out + (size_t)b * NP;
    // base: g0*C(e0,p)+g1*C(e1,p);  C = mu - mu*S + br*sd (linear) | mu | last
    {
        int p = l;
        float v = 0.f; int ee = i0; float gw = w0;
#pragma unroll
        for (int k2 = 0; k2 < 2; k2++) {
            if (ee < NEL)      v += gw * (mu + br[ee * NP + p] * sd - mu * Ssum[ee * NP + p]);
            else if (ee == NEL) v += gw * mu;
            else               v += gw * last;
            ee = i1; gw = w1;
        }
        op[p] = v;
    }
    if (l < 32) {
        int p = 64 + l;
        float v = 0.f; int ee = i0; float gw = w0;
#pragma unroll
        for (int k2 = 0; k2 < 2; k2++) {
            if (ee < NEL)      v += gw * (mu + br[ee * NP + p] * sd - mu * Ssum[ee * NP + p]);
            else if (ee == NEL) v += gw * mu;
            else               v += gw * last;
            ee = i1; gw = w1;
        }
        op[p] = v;
    }
    if (l < 2) {
        int ee = l ? i1 : i0; float gw = l ? w1 : w0;
        if (ee < NEL) {
            int pos = atomicAdd(&cnt[ee], 1);
            idxl[ee * NB_B + pos] = b;
            wl[ee * NB_B + pos] = gw;
        }
    }
}

// f64 phasor-DFT refinement for flagged (near-tie) rows.
__global__ __launch_bounds__(256) void k_refine(
    const float* __restrict__ x, const double2* __restrict__ twd,
    const float* __restrict__ Wg, const float* __restrict__ bg,
    const float* __restrict__ Ssum, const float* __restrict__ br,
    float* __restrict__ out,
    int* __restrict__ cnt, int* __restrict__ idxl, float* __restrict__ wl,
    const int* __restrict__ flaglist, const int* __restrict__ flagcnt)
{
    __shared__ double s_x[512];
    __shared__ double s_I[256];
    __shared__ double s_red[16];
    __shared__ double s_g[16];
    __shared__ int    s_ei[2];
    __shared__ float  s_w2[2];
    const int nf = *flagcnt;
    const int t = threadIdx.x;
    const int wid = t >> 6, lane = t & 63;
    for (int fi = blockIdx.x; fi < nf; fi += gridDim.x) {
        const int b = flaglist[fi];
        const float* xp = x + (size_t)b * NL;
        double v0 = (double)xp[t], v1 = (double)xp[t + 256];
        double lsum = v0 + v1, lsq = v0 * v0 + v1 * v1;
        for (int m = 1; m < 64; m <<= 1) { lsum += __shfl_xor(lsum, m); lsq += __shfl_xor(lsq, m); }
        if (lane == 0) { s_red[wid] = lsum; s_red[4 + wid] = lsq; }
        __syncthreads();
        double mu = (s_red[0] + s_red[1] + s_red[2] + s_red[3]) * (1.0 / 512.0);
        double var = (s_red[4] + s_red[5] + s_red[6] + s_red[7]) * (1.0 / 512.0) - mu * mu;
        double sd = sqrt(var + 1e-5);
        double last = (double)xp[511];
        s_x[t] = v0 - mu; s_x[t + 256] = v1 - mu;
        __syncthreads();
        // X[f] = sum_n x0[n] * W^(f n), rotating phasor (f = t, 256 bins)
        double2 w = twd[t];
        double pr = 1.0, pi = 0.0, cr = 0.0, ci = 0.0;
        for (int n = 0; n < 512; n++) {
            double xv = s_x[n];
            cr += xv * pr; ci += xv * pi;
            double t2 = pr * w.x - pi * w.y;
            pi = pr * w.y + pi * w.x;
            pr = t2;
        }
        double I = cr * cr + ci * ci;
        s_I[t] = I;
        double ls = I;
        for (int m = 1; m < 64; m <<= 1) ls += __shfl_xor(ls, m);
        if (lane == 0) s_red[8 + wid] = ls;
        __syncthreads();
        double stot = s_red[8] + s_red[9] + s_red[10] + s_red[11];
        if (stot == 0.0) stot = 1.0;
        if (t < 16) {
            double acc = 0.0;
            const float* wrow = Wg + t * NF;
            for (int f = 0; f < NF; f++) acc += s_I[f] * (double)wrow[f];
            s_g[t] = (acc / stot + (double)bg[t]) * (1.0 / 0.07);
        }
        __syncthreads();
        if (t == 0) {
            double c0 = -1e300, c1 = -1e300; int j0 = 0, j1 = 0;
            for (int i = 0; i < 16; i++) {
                double v = s_g[i];
                if (v > c0) { c1 = c0; j1 = j0; c0 = v; j0 = i; }
                else if (v > c1) { c1 = v; j1 = i; }
            }
            double e1 = exp(c1 - c0);
            double w0 = 1.0 / (1.0 + e1);
            s_ei[0] = j0; s_ei[1] = j1;
            s_w2[0] = (float)w0; s_w2[1] = (float)(e1 * w0);
        }
        __syncthreads();
        int i0 = s_ei[0], i1 = s_ei[1];
        float w0f = s_w2[0], w1f = s_w2[1];
        float muf = (float)mu, sdf = (float)sd, lastf = (float)last;
        if (t < NP) {
            float v = 0.f; int ee = i0; float gw = w0f;
            for (int k2 = 0; k2 < 2; k2++) {
                if (ee < NEL)      v += gw * (muf + br[ee * NP + t] * sdf - muf * Ssum[ee * NP + t]);
                else if (ee == NEL) v += gw * muf;
                else               v += gw * lastf;
                ee = i1; gw = w1f;
            }
            out[(size_t)b * NP + t] = v;
        }
        if (t < 2) {
            int ee = t ? i1 : i0; float gw = t ? w1f : w0f;
            if (ee < NEL) {
                int pos = atomicAdd(&cnt[ee], 1);
                idxl[ee * NB_B + pos] = b;
                wl[ee * NB_B + pos] = gw;
            }
        }
        __syncthreads();
    }
}

// Gathered per-expert GEMM: 64 rows x 96 outputs x K=512, fp32, atomic += g*dot.
#define KC   64
#define NBCH 64
__global__ __launch_bounds__(256) void k_gemm(
    const float* __restrict__ x, const float* __restrict__ Wr,
    float* __restrict__ out,
    const int* __restrict__ cnt, const int* __restrict__ idxl,
    const float* __restrict__ wl)
{
    __shared__ float sA[KC * 64];    // [l][r]
    __shared__ float sB[KC * 98];    // [l][p], stride 98: conflict-free float2 reads
    __shared__ int   s_idx[64];
    __shared__ float s_w[64];
    const int e = blockIdx.x / NBCH;
    const int cb = blockIdx.x % NBCH;
    const int n = cnt[e];
    const int nch = (n + 63) >> 6;
    const int t = threadIdx.x;
    const int tr = t >> 4, tc = t & 15;
    const int rq = t & 63, q = t >> 6;
    const int* il = idxl + (size_t)e * NB_B;
    const float* wlp = wl + (size_t)e * NB_B;
    const float4* wbase = (const float4*)(Wr + (size_t)e * NP * NL);

    for (int cc = cb; cc < nch; cc += NBCH) {
        if (t < 64) {
            int g = cc * 64 + t;
            bool vld = g < n;
            s_idx[t] = vld ? il[g] : il[0];
            s_w[t] = vld ? wlp[g] : 0.f;
        }
        __syncthreads();
        float acc[4][6];
#pragma unroll
        for (int i = 0; i < 4; i++)
#pragma unroll
            for (int j = 0; j < 6; j++) acc[i][j] = 0.f;

        for (int kb = 0; kb < NL; kb += KC) {
            {   // stage A (gathered x rows), lanes r-consecutive -> 2-way free
                const float4* xrow = (const float4*)(x + (size_t)s_idx[rq] * NL) + (kb >> 2);
#pragma unroll
                for (int i = 0; i < 4; i++) {
                    float4 v = xrow[q * 4 + i];
                    int ll = q * 16 + i * 4;
                    sA[(ll + 0) * 64 + rq] = v.x; sA[(ll + 1) * 64 + rq] = v.y;
                    sA[(ll + 2) * 64 + rq] = v.z; sA[(ll + 3) * 64 + rq] = v.w;
                }
            }
            // stage B (Wr tile, transpose to [l][p])
#pragma unroll
            for (int it = 0; it < 6; it++) {
                int f = t + it * 256;            // f < 1536
                int p = f >> 4, c4 = f & 15;
                float4 v = wbase[(size_t)p * (NL / 4) + (kb >> 2) + c4];
                int ll = c4 * 4;
                sB[(ll + 0) * 98 + p] = v.x; sB[(ll + 1) * 98 + p] = v.y;
                sB[(ll + 2) * 98 + p] = v.z; sB[(ll + 3) * 98 + p] = v.w;
            }
            __syncthreads();
#pragma unroll 2
            for (int ll = 0; ll < KC; ll++) {
                float4 a = *(const float4*)&sA[ll * 64 + tr * 4];
                float2 bv0 = *(const float2*)&sB[ll * 98 + tc * 6 + 0];
                float2 bv1 = *(const float2*)&sB[ll * 98 + tc * 6 + 2];
                float2 bv2 = *(const float2*)&sB[ll * 98 + tc * 6 + 4];
                float av[4] = {a.x, a.y, a.z, a.w};
                float bb[6] = {bv0.x, bv0.y, bv1.x, bv1.y, bv2.x, bv2.y};
#pragma unroll
                for (int i = 0; i < 4; i++)
#pragma unroll
                    for (int j = 0; j < 6; j++)
                        acc[i][j] += av[i] * bb[j];
            }
            __syncthreads();
        }
        // epilogue: out[b,p] += g * dot  (HW fp32 atomic; <=2 adders per element)
#pragma unroll
        for (int i = 0; i < 4; i++) {
            int r = tr * 4 + i;
            float wgt = s_w[r];
            float* orow = out + (size_t)s_idx[r] * NP + tc * 6;
#pragma unroll
            for (int j = 0; j < 6; j++)
                unsafeAtomicAdd(&orow[j], wgt * acc[i][j]);
        }
        __syncthreads();
    }
}

extern "C" void kernel_launch(void* const* d_in, const int* in_sizes, int n_in,
                              void* d_out, int out_size, void* d_ws, size_t ws_size,
                              hipStream_t stream)
{
    const float* x  = (const float*)d_in[0];
    const float* Wg = (const float*)d_in[1];
    const float* bg = (const float*)d_in[2];
    const float* Wr = (const float*)d_in[3];
    const float* br = (const float*)d_in[4];
    float* out = (float*)d_out;
    char* ws = (char*)d_ws;

    int*     cnt      = (int*)(ws + 0);
    int*     flagcnt  = (int*)(ws + 64);
    int*     flaglist = (int*)(ws + 128);
    float*   Ssum     = (float*)(ws + 262272);
    float*   WgT      = (float*)(ws + 267648);
    float*   bgT      = (float*)(ws + 284032);
    float2*  twf      = (float2*)(ws + 284096);
    double2* twd      = (double2*)(ws + 286144);
    int*     idxl     = (int*)(ws + 294336);
    float*   wl       = (float*)(ws + 294336 + (size_t)NEL * NB_B * 4);

    k_prep<<<dim3(32), dim3(256), 0, stream>>>(Wg, bg, Wr, Ssum, WgT, bgT, twf, twd, cnt, flagcnt);
    k_gate<<<dim3(NB_B), dim3(64), 0, stream>>>(x, WgT, bgT, twf, Ssum, br, out,
                                                cnt, idxl, wl, flaglist, flagcnt);
    k_refine<<<dim3(512), dim3(256), 0, stream>>>(x, twd, Wg, bg, Ssum, br, out,
                                                  cnt, idxl, wl, flaglist, flagcnt);
    k_gemm<<<dim3(NEL * NBCH), dim3(256), 0, stream>>>(x, Wr, out, cnt, idxl, wl);
}

// Round 2
// 809.170 us; speedup vs baseline: 1.7464x; 1.7464x over previous
//
#include <hip/hip_runtime.h>
#include <math.h>

#define NB_B 65536
#define NL   512
#define NP   96
#define NE   16
#define NEL  14
#define NF   256
#define TEMP_INV (1.0f/0.07f)
#define TAU  1e-5f
#define PI_D 3.14159265358979323846

// ---------------- workspace layout (bytes) ----------------
// 0        cnt[16] padded     (int, stride 64B -> separate cache lines)
// 1024     flagcnt            (int)
// 1088     Ssum[14*96]        (f32)
// 6464     WgT[256*16]        (f32)  Wg^T * (1/TEMP)
// 22848    bgT[16]            (f32)
// 22912    twf[256]           (float2)
// 24960    twd[512]           (double2)
// 33152    rec[65536]         (int2: packed experts, w0)
// 557440   idxl[14*65536]     (int)   [flaglist overlays first 256KB: consumed
// 4227456  wl[14*65536]       (f32)    by k_refine before k_bucket writes idxl]
// total ~7.53 MB

#define WS_CNT      0
#define WS_FLAGCNT  1024
#define WS_SSUM     1088
#define WS_WGT      6464
#define WS_BGT      22848
#define WS_TWF      22912
#define WS_TWD      24960
#define WS_REC      33152
#define WS_IDXL     557440
#define WS_WL       4227456

__global__ __launch_bounds__(256) void k_prep(
    const float* __restrict__ Wg, const float* __restrict__ bg,
    const float* __restrict__ Wr,
    float* __restrict__ Ssum, float* __restrict__ WgT, float* __restrict__ bgT,
    float2* __restrict__ twf, double2* __restrict__ twd,
    int* __restrict__ cnt, int* __restrict__ flagcnt)
{
    int g = blockIdx.x * 256 + threadIdx.x;
    if (g < NEL * NP) {
        const float4* w = (const float4*)(Wr + (size_t)g * NL);
        float s = 0.f;
        for (int i = 0; i < NL / 4; i++) { float4 v = w[i]; s += v.x + v.y + v.z + v.w; }
        Ssum[g] = s;
    }
    if (g < NF * NE) {
        int f = g >> 4, e = g & 15;
        WgT[g] = Wg[e * NF + f] * TEMP_INV;
    }
    if (g < NF) {
        double a = -2.0 * PI_D * (double)g / 512.0;
        twf[g] = make_float2((float)cos(a), (float)sin(a));
    }
    if (g < 512) {
        double a = -2.0 * PI_D * (double)g / 512.0;
        twd[g] = make_double2(cos(a), sin(a));
    }
    if (g < NE) cnt[g << 4] = 0;          // padded counters
    if (g < NE) bgT[g] = bg[g] * TEMP_INV;
    if (g == 31) *flagcnt = 0;
}

// Per-row wave: register FFT (512pt, 8 regs/lane), periodogram, gate, top-2,
// base output, dense 8B record. 4 rows per 256-thread block. No list atomics.
__global__ __launch_bounds__(256) void k_gate(
    const float* __restrict__ x,
    const float* __restrict__ WgT, const float* __restrict__ bgT,
    const float2* __restrict__ twf,
    const float* __restrict__ Ssum, const float* __restrict__ br,
    float* __restrict__ out,
    int2* __restrict__ rec,
    int* __restrict__ flaglist, int* __restrict__ flagcnt)
{
    __shared__ float2 s_tw[256];
    __shared__ float  s_I[4][292];   // per wave, padded f + (f>>3)
    __shared__ float  s_g[4][16];
    const int t = threadIdx.x;
    const int wv = t >> 6, l = t & 63;
    const int b = blockIdx.x * 4 + wv;
    s_tw[t] = twf[t];

    const float* xp = x + (size_t)b * NL;
    float xr[8], xi[8];
#pragma unroll
    for (int k = 0; k < 8; k++) xr[k] = xp[k * 64 + l];   // element n = k*64 + l

    float sum = 0.f, sq = 0.f;
#pragma unroll
    for (int k = 0; k < 8; k++) { sum += xr[k]; sq += xr[k] * xr[k]; }
#pragma unroll
    for (int m = 1; m < 64; m <<= 1) { sum += __shfl_xor(sum, m); sq += __shfl_xor(sq, m); }
    const float mu = sum * (1.f / 512.f);
    const float var = sq * (1.f / 512.f) - mu * mu;
    const float sd = sqrtf(var + 1e-5f);
    const float last = __shfl(xr[7], 63);
#pragma unroll
    for (int k = 0; k < 8; k++) { xr[k] -= mu; xi[k] = 0.f; }
    __syncthreads();

    // ---- DIF FFT, natural in, bit-reversed out ----
#pragma unroll
    for (int k = 0; k < 4; k++) {                       // stage 0: half=256
        float2 w = s_tw[k * 64 + l];
        float ur = xr[k], ui = xi[k], vr = xr[k + 4], vi = xi[k + 4];
        xr[k] = ur + vr; xi[k] = ui + vi;
        float dr = ur - vr, di = ui - vi;
        xr[k + 4] = dr * w.x - di * w.y; xi[k + 4] = dr * w.y + di * w.x;
    }
    {                                                   // stage 1: half=128
        const int kk[4] = {0, 1, 4, 5};
#pragma unroll
        for (int g2 = 0; g2 < 4; g2++) {
            int k = kk[g2];
            float2 w = s_tw[((k & 1) * 64 + l) << 1];
            float ur = xr[k], ui = xi[k], vr = xr[k + 2], vi = xi[k + 2];
            xr[k] = ur + vr; xi[k] = ui + vi;
            float dr = ur - vr, di = ui - vi;
            xr[k + 2] = dr * w.x - di * w.y; xi[k + 2] = dr * w.y + di * w.x;
        }
    }
    {                                                   // stage 2: half=64
        float2 w = s_tw[l << 2];
#pragma unroll
        for (int k = 0; k < 8; k += 2) {
            float ur = xr[k], ui = xi[k], vr = xr[k + 1], vi = xi[k + 1];
            xr[k] = ur + vr; xi[k] = ui + vi;
            float dr = ur - vr, di = ui - vi;
            xr[k + 1] = dr * w.x - di * w.y; xi[k + 1] = dr * w.y + di * w.x;
        }
    }
#pragma unroll
    for (int st = 3; st < 9; st++) {                    // stages 3..8 cross-lane
        const int half = 256 >> st;
        const int tt = (l & (half - 1)) << st;
        float2 w = s_tw[tt];
        const bool up = (l & half) != 0;
        const float cc = up ? w.x : 1.f;
        const float ss = up ? w.y : 0.f;
#pragma unroll
        for (int k = 0; k < 8; k++) {
            float pr = __shfl_xor(xr[k], half);
            float pi = __shfl_xor(xi[k], half);
            float ar = up ? (pr - xr[k]) : (xr[k] + pr);
            float ai = up ? (pi - xi[k]) : (xi[k] + pi);
            xr[k] = ar * cc - ai * ss;
            xi[k] = ar * ss + ai * cc;
        }
    }

    // periodogram: even-l lanes hold bins f<256 (f = bitrev9(i))
    float psum = 0.f;
    if ((l & 1) == 0) {
#pragma unroll
        for (int k = 0; k < 8; k++) {
            unsigned i = (unsigned)(k * 64 + l);
            int f = (int)(__brev(i) >> 23);
            float I = xr[k] * xr[k] + xi[k] * xi[k];
            s_I[wv][f + (f >> 3)] = I;
            psum += I;
        }
    }
#pragma unroll
    for (int m = 1; m < 64; m <<= 1) psum += __shfl_xor(psum, m);
    if (psum == 0.f) psum = 1.f;
    const float inv = 1.f / psum;
    __syncthreads();

    // gate: 16 experts x 4 lanes each, 64 bins per lane
    {
        int e = l >> 2, cq = l & 3;
        float acc = 0.f;
#pragma unroll 4
        for (int j = 0; j < 64; j++) {
            int f = cq * 64 + j;
            acc += s_I[wv][f + (f >> 3)] * WgT[f * 16 + e];
        }
        acc += __shfl_xor(acc, 1);
        acc += __shfl_xor(acc, 2);
        if (cq == 0) s_g[wv][e] = acc * inv + bgT[e];
    }
    __syncthreads();

    // top-2 (strict > keeps lowest index, matching lax.top_k), track 3rd for flag
    float b0 = -1e30f, b1 = -1e30f, b2 = -1e30f; int i0 = 0, i1 = 0;
    for (int i = 0; i < 16; i++) {
        float v = s_g[wv][i];
        if (v > b0) { b2 = b1; b1 = b0; i1 = i0; b0 = v; i0 = i; }
        else if (v > b1) { b2 = b1; b1 = v; i1 = i; }
        else if (v > b2) { b2 = v; }
    }
    float e1 = expf(b1 - b0);
    float w0 = 1.f / (1.f + e1), w1 = e1 * w0;

    float* op = out + (size_t)b * NP;
    // base: g0*C(e0,p)+g1*C(e1,p);  C = mu - mu*S + br*sd (linear) | mu | last
    {
        int p = l;
        float v = 0.f; int ee = i0; float gw = w0;
#pragma unroll
        for (int k2 = 0; k2 < 2; k2++) {
            if (ee < NEL)       v += gw * (mu + br[ee * NP + p] * sd - mu * Ssum[ee * NP + p]);
            else if (ee == NEL) v += gw * mu;
            else                v += gw * last;
            ee = i1; gw = w1;
        }
        op[p] = v;
    }
    if (l < 32) {
        int p = 64 + l;
        float v = 0.f; int ee = i0; float gw = w0;
#pragma unroll
        for (int k2 = 0; k2 < 2; k2++) {
            if (ee < NEL)       v += gw * (mu + br[ee * NP + p] * sd - mu * Ssum[ee * NP + p]);
            else if (ee == NEL) v += gw * mu;
            else                v += gw * last;
            ee = i1; gw = w1;
        }
        op[p] = v;
    }
    if (l == 0) {
        rec[b] = make_int2(i0 | (i1 << 8), __float_as_int(w0));
        if (b1 - b2 < TAU) {   // near-tie: defer to f64 refine (rare, ~1e-3 of rows)
            int pos = atomicAdd(flagcnt, 1);
            flaglist[pos] = b;
        }
    }
}

// f64 phasor-DFT refinement for flagged (near-tie) rows.
__global__ __launch_bounds__(256) void k_refine(
    const float* __restrict__ x, const double2* __restrict__ twd,
    const float* __restrict__ Wg, const float* __restrict__ bg,
    const float* __restrict__ Ssum, const float* __restrict__ br,
    float* __restrict__ out, int2* __restrict__ rec,
    const int* __restrict__ flaglist, const int* __restrict__ flagcnt)
{
    __shared__ double s_x[512];
    __shared__ double s_I[256];
    __shared__ double s_red[16];
    __shared__ double s_g[16];
    const int nf = *flagcnt;
    const int t = threadIdx.x;
    const int wid = t >> 6, lane = t & 63;
    for (int fi = blockIdx.x; fi < nf; fi += gridDim.x) {
        const int b = flaglist[fi];
        const float* xp = x + (size_t)b * NL;
        double v0 = (double)xp[t], v1 = (double)xp[t + 256];
        double lsum = v0 + v1, lsq = v0 * v0 + v1 * v1;
        for (int m = 1; m < 64; m <<= 1) { lsum += __shfl_xor(lsum, m); lsq += __shfl_xor(lsq, m); }
        if (lane == 0) { s_red[wid] = lsum; s_red[4 + wid] = lsq; }
        __syncthreads();
        double mu = (s_red[0] + s_red[1] + s_red[2] + s_red[3]) * (1.0 / 512.0);
        double var = (s_red[4] + s_red[5] + s_red[6] + s_red[7]) * (1.0 / 512.0) - mu * mu;
        double sd = sqrt(var + 1e-5);
        double last = (double)xp[511];
        s_x[t] = v0 - mu; s_x[t + 256] = v1 - mu;
        __syncthreads();
        double2 w = twd[t];
        double pr = 1.0, pi = 0.0, cr = 0.0, ci = 0.0;
        for (int n = 0; n < 512; n++) {
            double xv = s_x[n];
            cr += xv * pr; ci += xv * pi;
            double t2 = pr * w.x - pi * w.y;
            pi = pr * w.y + pi * w.x;
            pr = t2;
        }
        double I = cr * cr + ci * ci;
        s_I[t] = I;
        double ls = I;
        for (int m = 1; m < 64; m <<= 1) ls += __shfl_xor(ls, m);
        if (lane == 0) s_red[8 + wid] = ls;
        __syncthreads();
        double stot = s_red[8] + s_red[9] + s_red[10] + s_red[11];
        if (stot == 0.0) stot = 1.0;
        if (t < 16) {
            double acc = 0.0;
            const float* wrow = Wg + t * NF;
            for (int f = 0; f < NF; f++) acc += s_I[f] * (double)wrow[f];
            s_g[t] = (acc / stot + (double)bg[t]) * (1.0 / 0.07);
        }
        __syncthreads();
        if (t == 0) {
            double c0 = -1e300, c1 = -1e300; int j0 = 0, j1 = 0;
            for (int i = 0; i < 16; i++) {
                double v = s_g[i];
                if (v > c0) { c1 = c0; j1 = j0; c0 = v; j0 = i; }
                else if (v > c1) { c1 = v; j1 = i; }
            }
            double e1 = exp(c1 - c0);
            double w0 = 1.0 / (1.0 + e1);
            s_red[12] = w0;
            s_red[13] = (double)j0; s_red[14] = (double)j1;
        }
        __syncthreads();
        int i0 = (int)s_red[13], i1 = (int)s_red[14];
        float w0f = (float)s_red[12], w1f = 1.f - w0f;
        float muf = (float)mu, sdf = (float)sd, lastf = (float)last;
        if (t < NP) {
            float v = 0.f; int ee = i0; float gw = w0f;
            for (int k2 = 0; k2 < 2; k2++) {
                if (ee < NEL)       v += gw * (muf + br[ee * NP + t] * sdf - muf * Ssum[ee * NP + t]);
                else if (ee == NEL) v += gw * muf;
                else                v += gw * lastf;
                ee = i1; gw = w1f;
            }
            out[(size_t)b * NP + t] = v;
        }
        if (t == 0) rec[b] = make_int2(i0 | (i1 << 8), __float_as_int(w0f));
        __syncthreads();
    }
}

// Build per-expert row lists from dense records: LDS histogram per block,
// <=14 padded-line global atomics per block (~3.5K total vs 131K before).
__global__ __launch_bounds__(256) void k_bucket(
    const int2* __restrict__ rec, int* __restrict__ cnt,
    int* __restrict__ idxl, float* __restrict__ wl)
{
    __shared__ int hcnt[16], hoff[16], hbase[16];
    const int t = threadIdx.x;
    const int b = blockIdx.x * 256 + t;
    int2 r = rec[b];
    int i0 = r.x & 0xff, i1 = (r.x >> 8) & 0xff;
    float w0 = __int_as_float(r.y), w1 = 1.f - w0;
    if (t < 16) { hcnt[t] = 0; hoff[t] = 0; }
    __syncthreads();
    if (i0 < NEL) atomicAdd(&hcnt[i0], 1);
    if (i1 < NEL) atomicAdd(&hcnt[i1], 1);
    __syncthreads();
    if (t < 16) hbase[t] = hcnt[t] ? atomicAdd(&cnt[t << 4], hcnt[t]) : 0;
    __syncthreads();
    if (i0 < NEL) {
        int p = hbase[i0] + atomicAdd(&hoff[i0], 1);
        idxl[(size_t)i0 * NB_B + p] = b;
        wl[(size_t)i0 * NB_B + p] = w0;
    }
    if (i1 < NEL) {
        int p = hbase[i1] + atomicAdd(&hoff[i1], 1);
        idxl[(size_t)i1 * NB_B + p] = b;
        wl[(size_t)i1 * NB_B + p] = w1;
    }
}

// Gathered per-expert GEMM: 64 rows x 96 outputs x K=512, fp32, atomic += g*dot.
#define KC   64
#define NBCH 64
__global__ __launch_bounds__(256) void k_gemm(
    const float* __restrict__ x, const float* __restrict__ Wr,
    float* __restrict__ out,
    const int* __restrict__ cnt, const int* __restrict__ idxl,
    const float* __restrict__ wl)
{
    __shared__ float sA[KC * 64];    // [l][r]
    __shared__ float sB[KC * 98];    // [l][p]
    __shared__ int   s_idx[64];
    __shared__ float s_w[64];
    const int e = blockIdx.x / NBCH;
    const int cb = blockIdx.x % NBCH;
    const int n = cnt[e << 4];
    const int nch = (n + 63) >> 6;
    const int t = threadIdx.x;
    const int tr = t >> 4, tc = t & 15;
    const int rq = t & 63, q = t >> 6;
    const int* il = idxl + (size_t)e * NB_B;
    const float* wlp = wl + (size_t)e * NB_B;
    const float4* wbase = (const float4*)(Wr + (size_t)e * NP * NL);

    for (int cc = cb; cc < nch; cc += NBCH) {
        if (t < 64) {
            int g = cc * 64 + t;
            bool vld = g < n;
            s_idx[t] = vld ? il[g] : il[0];
            s_w[t] = vld ? wlp[g] : 0.f;
        }
        __syncthreads();
        float acc[4][6];
#pragma unroll
        for (int i = 0; i < 4; i++)
#pragma unroll
            for (int j = 0; j < 6; j++) acc[i][j] = 0.f;

        for (int kb = 0; kb < NL; kb += KC) {
            {   // stage A (gathered x rows)
                const float4* xrow = (const float4*)(x + (size_t)s_idx[rq] * NL) + (kb >> 2);
#pragma unroll
                for (int i = 0; i < 4; i++) {
                    float4 v = xrow[q * 4 + i];
                    int ll = q * 16 + i * 4;
                    sA[(ll + 0) * 64 + rq] = v.x; sA[(ll + 1) * 64 + rq] = v.y;
                    sA[(ll + 2) * 64 + rq] = v.z; sA[(ll + 3) * 64 + rq] = v.w;
                }
            }
#pragma unroll
            for (int it = 0; it < 6; it++) {     // stage B (Wr tile -> [l][p])
                int f = t + it * 256;
                int p = f >> 4, c4 = f & 15;
                float4 v = wbase[(size_t)p * (NL / 4) + (kb >> 2) + c4];
                int ll = c4 * 4;
                sB[(ll + 0) * 98 + p] = v.x; sB[(ll + 1) * 98 + p] = v.y;
                sB[(ll + 2) * 98 + p] = v.z; sB[(ll + 3) * 98 + p] = v.w;
            }
            __syncthreads();
#pragma unroll 2
            for (int ll = 0; ll < KC; ll++) {
                float4 a = *(const float4*)&sA[ll * 64 + tr * 4];
                float2 bv0 = *(const float2*)&sB[ll * 98 + tc * 6 + 0];
                float2 bv1 = *(const float2*)&sB[ll * 98 + tc * 6 + 2];
                float2 bv2 = *(const float2*)&sB[ll * 98 + tc * 6 + 4];
                float av[4] = {a.x, a.y, a.z, a.w};
                float bb[6] = {bv0.x, bv0.y, bv1.x, bv1.y, bv2.x, bv2.y};
#pragma unroll
                for (int i = 0; i < 4; i++)
#pragma unroll
                    for (int j = 0; j < 6; j++)
                        acc[i][j] += av[i] * bb[j];
            }
            __syncthreads();
        }
#pragma unroll
        for (int i = 0; i < 4; i++) {
            int r = tr * 4 + i;
            float wgt = s_w[r];
            float* orow = out + (size_t)s_idx[r] * NP + tc * 6;
#pragma unroll
            for (int j = 0; j < 6; j++)
                unsafeAtomicAdd(&orow[j], wgt * acc[i][j]);
        }
        __syncthreads();
    }
}

extern "C" void kernel_launch(void* const* d_in, const int* in_sizes, int n_in,
                              void* d_out, int out_size, void* d_ws, size_t ws_size,
                              hipStream_t stream)
{
    const float* x  = (const float*)d_in[0];
    const float* Wg = (const float*)d_in[1];
    const float* bg = (const float*)d_in[2];
    const float* Wr = (const float*)d_in[3];
    const float* br = (const float*)d_in[4];
    float* out = (float*)d_out;
    char* ws = (char*)d_ws;

    int*     cnt      = (int*)(ws + WS_CNT);
    int*     flagcnt  = (int*)(ws + WS_FLAGCNT);
    float*   Ssum     = (float*)(ws + WS_SSUM);
    float*   WgT      = (float*)(ws + WS_WGT);
    float*   bgT      = (float*)(ws + WS_BGT);
    float2*  twf      = (float2*)(ws + WS_TWF);
    double2* twd      = (double2*)(ws + WS_TWD);
    int2*    rec      = (int2*)(ws + WS_REC);
    int*     idxl     = (int*)(ws + WS_IDXL);
    float*   wl       = (float*)(ws + WS_WL);
    int*     flaglist = idxl;   // overlay: consumed by k_refine before k_bucket writes idxl

    k_prep<<<dim3(32), dim3(256), 0, stream>>>(Wg, bg, Wr, Ssum, WgT, bgT, twf, twd, cnt, flagcnt);
    k_gate<<<dim3(NB_B / 4), dim3(256), 0, stream>>>(x, WgT, bgT, twf, Ssum, br, out,
                                                     rec, flaglist, flagcnt);
    k_refine<<<dim3(512), dim3(256), 0, stream>>>(x, twd, Wg, bg, Ssum, br, out, rec,
                                                  flaglist, flagcnt);
    k_bucket<<<dim3(NB_B / 256), dim3(256), 0, stream>>>(rec, cnt, idxl, wl);
    k_gemm<<<dim3(NEL * NBCH), dim3(256), 0, stream>>>(x, Wr, out, cnt, idxl, wl);
}

// Round 3
// 433.917 us; speedup vs baseline: 3.2567x; 1.8648x over previous
//
#include <hip/hip_runtime.h>
#include <math.h>

#define NB_B 65536
#define NL   512
#define NP   96
#define NE   16
#define NEL  14
#define NF   256
#define TEMP_INV (1.0f/0.07f)
#define TAU  1e-5f
#define PI_D 3.14159265358979323846

typedef __attribute__((ext_vector_type(8))) short bf16x8;
typedef __attribute__((ext_vector_type(4))) float f32x4;

// ---------------- workspace layout (bytes) ----------------
// 0        cnt[16] padded     (int, stride 64B)
// 1024     flagcnt            (int)
// 1088     Ssum[14*96]        (f32)
// 6464     WgT[256*16]        (f32)
// 22848    bgT[16]            (f32)
// 22912    twf[256]           (float2)
// 24960    twd[512]           (double2)
// 33152    rec[65536]         (int2)
// 557440   idxl[14*65536]     (int)  [flaglist overlays head]
// 4227456  wl[14*65536]       (f32)
// 7897472  Wrb[14*96*512]     (bf16) total ~9.27 MB

#define WS_CNT      0
#define WS_FLAGCNT  1024
#define WS_SSUM     1088
#define WS_WGT      6464
#define WS_BGT      22848
#define WS_TWF      22912
#define WS_TWD      24960
#define WS_REC      33152
#define WS_IDXL     557440
#define WS_WL       4227456
#define WS_WRB      7897472

__device__ __forceinline__ unsigned short f2bf(float f) {
    unsigned u = __float_as_uint(f);
    unsigned r = (u + 0x7fffu + ((u >> 16) & 1u)) >> 16;
    return (unsigned short)r;
}

__global__ __launch_bounds__(256) void k_prep(
    const float* __restrict__ Wg, const float* __restrict__ bg,
    const float* __restrict__ Wr,
    float* __restrict__ Ssum, float* __restrict__ WgT, float* __restrict__ bgT,
    float2* __restrict__ twf, double2* __restrict__ twd,
    int* __restrict__ cnt, int* __restrict__ flagcnt)
{
    int g = blockIdx.x * 256 + threadIdx.x;
    if (g < NEL * NP) {
        const float4* w = (const float4*)(Wr + (size_t)g * NL);
        float s = 0.f;
        for (int i = 0; i < NL / 4; i++) { float4 v = w[i]; s += v.x + v.y + v.z + v.w; }
        Ssum[g] = s;
    }
    if (g < NF * NE) {
        int f = g >> 4, e = g & 15;
        WgT[g] = Wg[e * NF + f] * TEMP_INV;
    }
    if (g < NF) {
        double a = -2.0 * PI_D * (double)g / 512.0;
        twf[g] = make_float2((float)cos(a), (float)sin(a));
    }
    if (g < 512) {
        double a = -2.0 * PI_D * (double)g / 512.0;
        twd[g] = make_double2(cos(a), sin(a));
    }
    if (g < NE) cnt[g << 4] = 0;
    if (g < NE) bgT[g] = bg[g] * TEMP_INV;
    if (g == 31) *flagcnt = 0;
}

// Wr f32 -> bf16 (RNE), 4 elements/thread. 672 blocks x 256 = exactly 14*96*512/4.
__global__ __launch_bounds__(256) void k_cvt(
    const float4* __restrict__ Wr, ushort4* __restrict__ Wrb)
{
    int g = blockIdx.x * 256 + threadIdx.x;
    float4 v = Wr[g];
    ushort4 o;
    o.x = f2bf(v.x); o.y = f2bf(v.y); o.z = f2bf(v.z); o.w = f2bf(v.w);
    Wrb[g] = o;
}

// Per-row wave: register FFT (512pt), periodogram, gate, top-2, base output,
// dense 8B record. 4 rows per 256-thread block.
__global__ __launch_bounds__(256) void k_gate(
    const float* __restrict__ x,
    const float* __restrict__ WgT, const float* __restrict__ bgT,
    const float2* __restrict__ twf,
    const float* __restrict__ Ssum, const float* __restrict__ br,
    float* __restrict__ out,
    int2* __restrict__ rec,
    int* __restrict__ flaglist, int* __restrict__ flagcnt)
{
    __shared__ float2 s_tw[256];
    __shared__ float  s_I[4][292];
    __shared__ float  s_g[4][16];
    const int t = threadIdx.x;
    const int wv = t >> 6, l = t & 63;
    const int b = blockIdx.x * 4 + wv;
    s_tw[t] = twf[t];

    const float* xp = x + (size_t)b * NL;
    float xr[8], xi[8];
#pragma unroll
    for (int k = 0; k < 8; k++) xr[k] = xp[k * 64 + l];

    float sum = 0.f, sq = 0.f;
#pragma unroll
    for (int k = 0; k < 8; k++) { sum += xr[k]; sq += xr[k] * xr[k]; }
#pragma unroll
    for (int m = 1; m < 64; m <<= 1) { sum += __shfl_xor(sum, m); sq += __shfl_xor(sq, m); }
    const float mu = sum * (1.f / 512.f);
    const float var = sq * (1.f / 512.f) - mu * mu;
    const float sd = sqrtf(var + 1e-5f);
    const float last = __shfl(xr[7], 63);
#pragma unroll
    for (int k = 0; k < 8; k++) { xr[k] -= mu; xi[k] = 0.f; }
    __syncthreads();

    // ---- DIF FFT, natural in, bit-reversed out ----
#pragma unroll
    for (int k = 0; k < 4; k++) {                       // stage 0: half=256
        float2 w = s_tw[k * 64 + l];
        float ur = xr[k], ui = xi[k], vr = xr[k + 4], vi = xi[k + 4];
        xr[k] = ur + vr; xi[k] = ui + vi;
        float dr = ur - vr, di = ui - vi;
        xr[k + 4] = dr * w.x - di * w.y; xi[k + 4] = dr * w.y + di * w.x;
    }
    {                                                   // stage 1: half=128
        const int kk[4] = {0, 1, 4, 5};
#pragma unroll
        for (int g2 = 0; g2 < 4; g2++) {
            int k = kk[g2];
            float2 w = s_tw[((k & 1) * 64 + l) << 1];
            float ur = xr[k], ui = xi[k], vr = xr[k + 2], vi = xi[k + 2];
            xr[k] = ur + vr; xi[k] = ui + vi;
            float dr = ur - vr, di = ui - vi;
            xr[k + 2] = dr * w.x - di * w.y; xi[k + 2] = dr * w.y + di * w.x;
        }
    }
    {                                                   // stage 2: half=64
        float2 w = s_tw[l << 2];
#pragma unroll
        for (int k = 0; k < 8; k += 2) {
            float ur = xr[k], ui = xi[k], vr = xr[k + 1], vi = xi[k + 1];
            xr[k] = ur + vr; xi[k] = ui + vi;
            float dr = ur - vr, di = ui - vi;
            xr[k + 1] = dr * w.x - di * w.y; xi[k + 1] = dr * w.y + di * w.x;
        }
    }
#pragma unroll
    for (int st = 3; st < 9; st++) {                    // stages 3..8 cross-lane
        const int half = 256 >> st;
        const int tt = (l & (half - 1)) << st;
        float2 w = s_tw[tt];
        const bool up = (l & half) != 0;
        const float cc = up ? w.x : 1.f;
        const float ss = up ? w.y : 0.f;
#pragma unroll
        for (int k = 0; k < 8; k++) {
            float pr = __shfl_xor(xr[k], half);
            float pi = __shfl_xor(xi[k], half);
            float ar = up ? (pr - xr[k]) : (xr[k] + pr);
            float ai = up ? (pi - xi[k]) : (xi[k] + pi);
            xr[k] = ar * cc - ai * ss;
            xi[k] = ar * ss + ai * cc;
        }
    }

    float psum = 0.f;
    if ((l & 1) == 0) {
#pragma unroll
        for (int k = 0; k < 8; k++) {
            unsigned i = (unsigned)(k * 64 + l);
            int f = (int)(__brev(i) >> 23);
            float I = xr[k] * xr[k] + xi[k] * xi[k];
            s_I[wv][f + (f >> 3)] = I;
            psum += I;
        }
    }
#pragma unroll
    for (int m = 1; m < 64; m <<= 1) psum += __shfl_xor(psum, m);
    if (psum == 0.f) psum = 1.f;
    const float inv = 1.f / psum;
    __syncthreads();

    {
        int e = l >> 2, cq = l & 3;
        float acc = 0.f;
#pragma unroll 4
        for (int j = 0; j < 64; j++) {
            int f = cq * 64 + j;
            acc += s_I[wv][f + (f >> 3)] * WgT[f * 16 + e];
        }
        acc += __shfl_xor(acc, 1);
        acc += __shfl_xor(acc, 2);
        if (cq == 0) s_g[wv][e] = acc * inv + bgT[e];
    }
    __syncthreads();

    float b0 = -1e30f, b1 = -1e30f, b2 = -1e30f; int i0 = 0, i1 = 0;
    for (int i = 0; i < 16; i++) {
        float v = s_g[wv][i];
        if (v > b0) { b2 = b1; b1 = b0; i1 = i0; b0 = v; i0 = i; }
        else if (v > b1) { b2 = b1; b1 = v; i1 = i; }
        else if (v > b2) { b2 = v; }
    }
    float e1 = expf(b1 - b0);
    float w0 = 1.f / (1.f + e1), w1 = e1 * w0;

    float* op = out + (size_t)b * NP;
    {
        int p = l;
        float v = 0.f; int ee = i0; float gw = w0;
#pragma unroll
        for (int k2 = 0; k2 < 2; k2++) {
            if (ee < NEL)       v += gw * (mu + br[ee * NP + p] * sd - mu * Ssum[ee * NP + p]);
            else if (ee == NEL) v += gw * mu;
            else                v += gw * last;
            ee = i1; gw = w1;
        }
        op[p] = v;
    }
    if (l < 32) {
        int p = 64 + l;
        float v = 0.f; int ee = i0; float gw = w0;
#pragma unroll
        for (int k2 = 0; k2 < 2; k2++) {
            if (ee < NEL)       v += gw * (mu + br[ee * NP + p] * sd - mu * Ssum[ee * NP + p]);
            else if (ee == NEL) v += gw * mu;
            else                v += gw * last;
            ee = i1; gw = w1;
        }
        op[p] = v;
    }
    if (l == 0) {
        rec[b] = make_int2(i0 | (i1 << 8), __float_as_int(w0));
        if (b1 - b2 < TAU) {
            int pos = atomicAdd(flagcnt, 1);
            flaglist[pos] = b;
        }
    }
}

// f64 phasor-DFT refinement for flagged (near-tie) rows.
__global__ __launch_bounds__(256) void k_refine(
    const float* __restrict__ x, const double2* __restrict__ twd,
    const float* __restrict__ Wg, const float* __restrict__ bg,
    const float* __restrict__ Ssum, const float* __restrict__ br,
    float* __restrict__ out, int2* __restrict__ rec,
    const int* __restrict__ flaglist, const int* __restrict__ flagcnt)
{
    __shared__ double s_x[512];
    __shared__ double s_I[256];
    __shared__ double s_red[16];
    __shared__ double s_g[16];
    const int nf = *flagcnt;
    const int t = threadIdx.x;
    const int wid = t >> 6, lane = t & 63;
    for (int fi = blockIdx.x; fi < nf; fi += gridDim.x) {
        const int b = flaglist[fi];
        const float* xp = x + (size_t)b * NL;
        double v0 = (double)xp[t], v1 = (double)xp[t + 256];
        double lsum = v0 + v1, lsq = v0 * v0 + v1 * v1;
        for (int m = 1; m < 64; m <<= 1) { lsum += __shfl_xor(lsum, m); lsq += __shfl_xor(lsq, m); }
        if (lane == 0) { s_red[wid] = lsum; s_red[4 + wid] = lsq; }
        __syncthreads();
        double mu = (s_red[0] + s_red[1] + s_red[2] + s_red[3]) * (1.0 / 512.0);
        double var = (s_red[4] + s_red[5] + s_red[6] + s_red[7]) * (1.0 / 512.0) - mu * mu;
        double sd = sqrt(var + 1e-5);
        double last = (double)xp[511];
        s_x[t] = v0 - mu; s_x[t + 256] = v1 - mu;
        __syncthreads();
        double2 w = twd[t];
        double pr = 1.0, pi = 0.0, cr = 0.0, ci = 0.0;
        for (int n = 0; n < 512; n++) {
            double xv = s_x[n];
            cr += xv * pr; ci += xv * pi;
            double t2 = pr * w.x - pi * w.y;
            pi = pr * w.y + pi * w.x;
            pr = t2;
        }
        double I = cr * cr + ci * ci;
        s_I[t] = I;
        double ls = I;
        for (int m = 1; m < 64; m <<= 1) ls += __shfl_xor(ls, m);
        if (lane == 0) s_red[8 + wid] = ls;
        __syncthreads();
        double stot = s_red[8] + s_red[9] + s_red[10] + s_red[11];
        if (stot == 0.0) stot = 1.0;
        if (t < 16) {
            double acc = 0.0;
            const float* wrow = Wg + t * NF;
            for (int f = 0; f < NF; f++) acc += s_I[f] * (double)wrow[f];
            s_g[t] = (acc / stot + (double)bg[t]) * (1.0 / 0.07);
        }
        __syncthreads();
        if (t == 0) {
            double c0 = -1e300, c1 = -1e300; int j0 = 0, j1 = 0;
            for (int i = 0; i < 16; i++) {
                double v = s_g[i];
                if (v > c0) { c1 = c0; j1 = j0; c0 = v; j0 = i; }
                else if (v > c1) { c1 = v; j1 = i; }
            }
            double e1 = exp(c1 - c0);
            double w0 = 1.0 / (1.0 + e1);
            s_red[12] = w0;
            s_red[13] = (double)j0; s_red[14] = (double)j1;
        }
        __syncthreads();
        int i0 = (int)s_red[13], i1 = (int)s_red[14];
        float w0f = (float)s_red[12], w1f = 1.f - w0f;
        float muf = (float)mu, sdf = (float)sd, lastf = (float)last;
        if (t < NP) {
            float v = 0.f; int ee = i0; float gw = w0f;
            for (int k2 = 0; k2 < 2; k2++) {
                if (ee < NEL)       v += gw * (muf + br[ee * NP + t] * sdf - muf * Ssum[ee * NP + t]);
                else if (ee == NEL) v += gw * muf;
                else                v += gw * lastf;
                ee = i1; gw = w1f;
            }
            out[(size_t)b * NP + t] = v;
        }
        if (t == 0) rec[b] = make_int2(i0 | (i1 << 8), __float_as_int(w0f));
        __syncthreads();
    }
}

// Per-expert row lists from dense records; padded-line global atomics.
__global__ __launch_bounds__(256) void k_bucket(
    const int2* __restrict__ rec, int* __restrict__ cnt,
    int* __restrict__ idxl, float* __restrict__ wl)
{
    __shared__ int hcnt[16], hoff[16], hbase[16];
    const int t = threadIdx.x;
    const int b = blockIdx.x * 256 + t;
    int2 r = rec[b];
    int i0 = r.x & 0xff, i1 = (r.x >> 8) & 0xff;
    float w0 = __int_as_float(r.y), w1 = 1.f - w0;
    if (t < 16) { hcnt[t] = 0; hoff[t] = 0; }
    __syncthreads();
    if (i0 < NEL) atomicAdd(&hcnt[i0], 1);
    if (i1 < NEL) atomicAdd(&hcnt[i1], 1);
    __syncthreads();
    if (t < 16) hbase[t] = hcnt[t] ? atomicAdd(&cnt[t << 4], hcnt[t]) : 0;
    __syncthreads();
    if (i0 < NEL) {
        int p = hbase[i0] + atomicAdd(&hoff[i0], 1);
        idxl[(size_t)i0 * NB_B + p] = b;
        wl[(size_t)i0 * NB_B + p] = w0;
    }
    if (i1 < NEL) {
        int p = hbase[i1] + atomicAdd(&hoff[i1], 1);
        idxl[(size_t)i1 * NB_B + p] = b;
        wl[(size_t)i1 * NB_B + p] = w1;
    }
}

// Gathered per-expert MFMA GEMM: 64 rows x 96 cols x K=512 bf16,
// wave w = rows w*16..+16, 6 col-tiles; LDS stride 72 (odd 16B multiple).
#define NBCH 128
__global__ __launch_bounds__(256) void k_gemm(
    const float* __restrict__ x, const unsigned short* __restrict__ Wrb,
    float* __restrict__ out,
    const int* __restrict__ cnt, const int* __restrict__ idxl,
    const float* __restrict__ wl)
{
    __shared__ __align__(16) unsigned short sA[64 * 72];   // [r][k]
    __shared__ __align__(16) unsigned short sB[96 * 72];   // [p][k]
    __shared__ int   s_idx[64];
    __shared__ float s_w[64];
    const int e = blockIdx.x / NBCH;
    const int cb = blockIdx.x % NBCH;
    const int n = cnt[e << 4];
    const int nch = (n + 63) >> 6;
    const int t = threadIdx.x;
    const int lane = t & 63, wv = t >> 6;
    const int quad = lane >> 4, l16 = lane & 15;
    const int ar = t >> 2, asub = t & 3;     // A staging: 4 threads/row, 16 k each
    const int* il = idxl + (size_t)e * NB_B;
    const float* wlp = wl + (size_t)e * NB_B;
    const unsigned short* wb = Wrb + (size_t)e * NP * NL;

    for (int cc = cb; cc < nch; cc += NBCH) {
        __syncthreads();                       // protect s_idx/s_w from prev readers
        if (t < 64) {
            int g = cc * 64 + t;
            bool vld = g < n;
            s_idx[t] = vld ? il[g] : il[0];
            s_w[t] = vld ? wlp[g] : 0.f;
        }
        __syncthreads();
        f32x4 acc[6];
#pragma unroll
        for (int j = 0; j < 6; j++) acc[j] = (f32x4){0.f, 0.f, 0.f, 0.f};
        const float* xrow = x + (size_t)s_idx[ar] * NL + asub * 16;

        for (int kb = 0; kb < NL; kb += 64) {
            {   // stage A: row ar, k in [kb+asub*16, +16), f32->bf16
                const float4* src = (const float4*)(xrow + kb);
                unsigned short tmp[16];
#pragma unroll
                for (int i = 0; i < 4; i++) {
                    float4 v = src[i];
                    tmp[i * 4 + 0] = f2bf(v.x); tmp[i * 4 + 1] = f2bf(v.y);
                    tmp[i * 4 + 2] = f2bf(v.z); tmp[i * 4 + 3] = f2bf(v.w);
                }
                unsigned short* dst = sA + ar * 72 + asub * 16;
                *(bf16x8*)dst       = *(bf16x8*)tmp;
                *(bf16x8*)(dst + 8) = *(bf16x8*)(tmp + 8);
            }
#pragma unroll
            for (int it = 0; it < 3; it++) {   // stage B: 96 p-rows x 64 k
                int f = t + it * 256;          // f < 768; p = f>>3, kg = f&7
                int p = f >> 3, kg = f & 7;
                bf16x8 v = *(const bf16x8*)(wb + (size_t)p * NL + kb + kg * 8);
                *(bf16x8*)(sB + p * 72 + kg * 8) = v;
            }
            __syncthreads();
#pragma unroll
            for (int ks = 0; ks < 2; ks++) {
                bf16x8 af = *(const bf16x8*)(sA + (wv * 16 + l16) * 72 + ks * 32 + quad * 8);
#pragma unroll
                for (int nt = 0; nt < 6; nt++) {
                    bf16x8 bf = *(const bf16x8*)(sB + (nt * 16 + l16) * 72 + ks * 32 + quad * 8);
                    acc[nt] = __builtin_amdgcn_mfma_f32_16x16x32_bf16(af, bf, acc[nt], 0, 0, 0);
                }
            }
            __syncthreads();
        }
        // epilogue: D[m][n], m = quad*4+reg (wave-local), n = l16
#pragma unroll
        for (int i = 0; i < 4; i++) {
            int rloc = wv * 16 + quad * 4 + i;
            float wgt = s_w[rloc];
            float* orow = out + (size_t)s_idx[rloc] * NP;
#pragma unroll
            for (int nt = 0; nt < 6; nt++)
                unsafeAtomicAdd(&orow[nt * 16 + l16], wgt * acc[nt][i]);
        }
    }
}

extern "C" void kernel_launch(void* const* d_in, const int* in_sizes, int n_in,
                              void* d_out, int out_size, void* d_ws, size_t ws_size,
                              hipStream_t stream)
{
    const float* x  = (const float*)d_in[0];
    const float* Wg = (const float*)d_in[1];
    const float* bg = (const float*)d_in[2];
    const float* Wr = (const float*)d_in[3];
    const float* br = (const float*)d_in[4];
    float* out = (float*)d_out;
    char* ws = (char*)d_ws;

    int*     cnt      = (int*)(ws + WS_CNT);
    int*     flagcnt  = (int*)(ws + WS_FLAGCNT);
    float*   Ssum     = (float*)(ws + WS_SSUM);
    float*   WgT      = (float*)(ws + WS_WGT);
    float*   bgT      = (float*)(ws + WS_BGT);
    float2*  twf      = (float2*)(ws + WS_TWF);
    double2* twd      = (double2*)(ws + WS_TWD);
    int2*    rec      = (int2*)(ws + WS_REC);
    int*     idxl     = (int*)(ws + WS_IDXL);
    float*   wl       = (float*)(ws + WS_WL);
    unsigned short* Wrb = (unsigned short*)(ws + WS_WRB);
    int*     flaglist = idxl;   // overlay: consumed before k_bucket writes idxl

    k_prep<<<dim3(32), dim3(256), 0, stream>>>(Wg, bg, Wr, Ssum, WgT, bgT, twf, twd, cnt, flagcnt);
    k_cvt<<<dim3(672), dim3(256), 0, stream>>>((const float4*)Wr, (ushort4*)Wrb);
    k_gate<<<dim3(NB_B / 4), dim3(256), 0, stream>>>(x, WgT, bgT, twf, Ssum, br, out,
                                                     rec, flaglist, flagcnt);
    k_refine<<<dim3(512), dim3(256), 0, stream>>>(x, twd, Wg, bg, Ssum, br, out, rec,
                                                  flaglist, flagcnt);
    k_bucket<<<dim3(NB_B / 256), dim3(256), 0, stream>>>(rec, cnt, idxl, wl);
    k_gemm<<<dim3(NEL * NBCH), dim3(256), 0, stream>>>(x, Wrb, out, cnt, idxl, wl);
}

// Round 4
// 375.275 us; speedup vs baseline: 3.7656x; 1.1563x over previous
//
#include <hip/hip_runtime.h>
#include <math.h>

#define NB_B 65536
#define NL   512
#define NP   96
#define NE   16
#define NEL  14
#define NF   256
#define TEMP_INV (1.0f/0.07f)
#define TAU  1e-5f
#define PI_D 3.14159265358979323846

typedef __attribute__((ext_vector_type(8))) short bf16x8;
typedef __attribute__((ext_vector_type(4))) float f32x4;

// ---------------- workspace layout (bytes) ----------------
// 0        cnt[16] padded     (int, stride 64B)
// 1024     flagcnt            (int)
// 1088     Ssum[14*96]        (f32)
// 6464     WgT[256*16]        (f32)
// 22848    bgT[16]            (f32)
// 22912    twf[256]           (float2)
// 24960    twd[512]           (double2)
// 33152    rec[65536]         (int2)
// 557440   idxl[14*65536]     (int)  [flaglist overlays head]
// 4227456  wl[14*65536]       (f32)
// 7897472  Wrb[14*96*512]     (bf16) total ~9.27 MB

#define WS_CNT      0
#define WS_FLAGCNT  1024
#define WS_SSUM     1088
#define WS_WGT      6464
#define WS_BGT      22848
#define WS_TWF      22912
#define WS_TWD      24960
#define WS_REC      33152
#define WS_IDXL     557440
#define WS_WL       4227456
#define WS_WRB      7897472

__device__ __forceinline__ unsigned short f2bf(float f) {
    unsigned u = __float_as_uint(f);
    unsigned r = (u + 0x7fffu + ((u >> 16) & 1u)) >> 16;
    return (unsigned short)r;
}

__global__ __launch_bounds__(256) void k_prep(
    const float* __restrict__ Wg, const float* __restrict__ bg,
    const float* __restrict__ Wr,
    float* __restrict__ Ssum, float* __restrict__ WgT, float* __restrict__ bgT,
    float2* __restrict__ twf, double2* __restrict__ twd,
    int* __restrict__ cnt, int* __restrict__ flagcnt)
{
    int g = blockIdx.x * 256 + threadIdx.x;
    if (g < NEL * NP) {
        const float4* w = (const float4*)(Wr + (size_t)g * NL);
        float s = 0.f;
        for (int i = 0; i < NL / 4; i++) { float4 v = w[i]; s += v.x + v.y + v.z + v.w; }
        Ssum[g] = s;
    }
    if (g < NF * NE) {
        int f = g >> 4, e = g & 15;
        WgT[g] = Wg[e * NF + f] * TEMP_INV;
    }
    if (g < NF) {
        double a = -2.0 * PI_D * (double)g / 512.0;
        twf[g] = make_float2((float)cos(a), (float)sin(a));
    }
    if (g < 512) {
        double a = -2.0 * PI_D * (double)g / 512.0;
        twd[g] = make_double2(cos(a), sin(a));
    }
    if (g < NE) cnt[g << 4] = 0;
    if (g < NE) bgT[g] = bg[g] * TEMP_INV;
    if (g == 31) *flagcnt = 0;
}

// Wr f32 -> bf16 (RNE), 4 elements/thread.
__global__ __launch_bounds__(256) void k_cvt(
    const float4* __restrict__ Wr, ushort4* __restrict__ Wrb)
{
    int g = blockIdx.x * 256 + threadIdx.x;
    float4 v = Wr[g];
    ushort4 o;
    o.x = f2bf(v.x); o.y = f2bf(v.y); o.z = f2bf(v.z); o.w = f2bf(v.w);
    Wrb[g] = o;
}

// Pack-2 real FFT per wave: rows (2w, 2w+1) as z = a + i*b, one 512-pt complex
// FFT, conjugate-symmetry split -> I_a, I_b. 4 waves (8 rows) per block.
__global__ __launch_bounds__(256) void k_gate(
    const float* __restrict__ x,
    const float* __restrict__ WgT, const float* __restrict__ bgT,
    const float2* __restrict__ twf,
    const float* __restrict__ Ssum, const float* __restrict__ br,
    float* __restrict__ out,
    int2* __restrict__ rec,
    int* __restrict__ flaglist, int* __restrict__ flagcnt)
{
    __shared__ float2 s_tw[256];
    __shared__ float2 s_z[4][576];      // Z by register-order idx i+(i>>3)
    __shared__ float  s_g[4][2][16];
    float* s_Iv = (float*)&s_z[0][0];   // alias: I after Z consumed (barrier-sep)

    const int t = threadIdx.x;
    const int wv = t >> 6, l = t & 63;
    const int b0 = blockIdx.x * 8 + wv * 2;    // this wave: rows b0, b0+1
    s_tw[t] = twf[t];

    const float* xa = x + (size_t)b0 * NL;
    const float* xb = xa + NL;
    float xr[8], xi[8];
#pragma unroll
    for (int k = 0; k < 8; k++) { xr[k] = xa[k * 64 + l]; xi[k] = xb[k * 64 + l]; }

    float sa = 0.f, qa = 0.f, sb = 0.f, qb = 0.f;
#pragma unroll
    for (int k = 0; k < 8; k++) {
        sa += xr[k]; qa += xr[k] * xr[k];
        sb += xi[k]; qb += xi[k] * xi[k];
    }
#pragma unroll
    for (int m = 1; m < 64; m <<= 1) {
        sa += __shfl_xor(sa, m); qa += __shfl_xor(qa, m);
        sb += __shfl_xor(sb, m); qb += __shfl_xor(qb, m);
    }
    const float mu_a = sa * (1.f / 512.f);
    const float sd_a = sqrtf(qa * (1.f / 512.f) - mu_a * mu_a + 1e-5f);
    const float mu_b = sb * (1.f / 512.f);
    const float sd_b = sqrtf(qb * (1.f / 512.f) - mu_b * mu_b + 1e-5f);
    const float last_a = __shfl(xr[7], 63);
    const float last_b = __shfl(xi[7], 63);
#pragma unroll
    for (int k = 0; k < 8; k++) { xr[k] -= mu_a; xi[k] -= mu_b; }
    __syncthreads();                    // s_tw ready

    // ---- DIF FFT (complex), natural in, bit-reversed out ----
#pragma unroll
    for (int k = 0; k < 4; k++) {                       // stage 0: half=256
        float2 w = s_tw[k * 64 + l];
        float ur = xr[k], ui = xi[k], vr = xr[k + 4], vi = xi[k + 4];
        xr[k] = ur + vr; xi[k] = ui + vi;
        float dr = ur - vr, di = ui - vi;
        xr[k + 4] = dr * w.x - di * w.y; xi[k + 4] = dr * w.y + di * w.x;
    }
    {                                                   // stage 1: half=128
        const int kk[4] = {0, 1, 4, 5};
#pragma unroll
        for (int g2 = 0; g2 < 4; g2++) {
            int k = kk[g2];
            float2 w = s_tw[((k & 1) * 64 + l) << 1];
            float ur = xr[k], ui = xi[k], vr = xr[k + 2], vi = xi[k + 2];
            xr[k] = ur + vr; xi[k] = ui + vi;
            float dr = ur - vr, di = ui - vi;
            xr[k + 2] = dr * w.x - di * w.y; xi[k + 2] = dr * w.y + di * w.x;
        }
    }
    {                                                   // stage 2: half=64
        float2 w = s_tw[l << 2];
#pragma unroll
        for (int k = 0; k < 8; k += 2) {
            float ur = xr[k], ui = xi[k], vr = xr[k + 1], vi = xi[k + 1];
            xr[k] = ur + vr; xi[k] = ui + vi;
            float dr = ur - vr, di = ui - vi;
            xr[k + 1] = dr * w.x - di * w.y; xi[k + 1] = dr * w.y + di * w.x;
        }
    }
#pragma unroll
    for (int st = 3; st < 9; st++) {                    // stages 3..8 cross-lane
        const int half = 256 >> st;
        const int tt = (l & (half - 1)) << st;
        float2 w = s_tw[tt];
        const bool up = (l & half) != 0;
        const float cc = up ? w.x : 1.f;
        const float ss = up ? w.y : 0.f;
#pragma unroll
        for (int k = 0; k < 8; k++) {
            float pr = __shfl_xor(xr[k], half);
            float pi = __shfl_xor(xi[k], half);
            float ar = up ? (pr - xr[k]) : (xr[k] + pr);
            float ai = up ? (pi - xi[k]) : (xi[k] + pi);
            xr[k] = ar * cc - ai * ss;
            xi[k] = ar * ss + ai * cc;
        }
    }

    // store Z in register order (i = k*64+l holds bin bitrev9(i)), padded
#pragma unroll
    for (int k = 0; k < 8; k++) {
        int i = k * 64 + l;
        s_z[wv][i + (i >> 3)] = make_float2(xr[k], xi[k]);
    }
    __syncthreads();

    // conjugate-symmetry split: lane l owns bins f = 4l..4l+3 (x4 scale cancels)
    float Ia[4], Ib[4];
    float psa = 0.f, psb = 0.f;
#pragma unroll
    for (int j = 0; j < 4; j++) {
        int f = (l << 2) | j;
        int i1 = (int)(__brev((unsigned)f) >> 23);
        int i2 = (int)(__brev((unsigned)((512 - f) & 511)) >> 23);
        float2 z1 = s_z[wv][i1 + (i1 >> 3)];
        float2 z2 = s_z[wv][i2 + (i2 >> 3)];
        float pr_ = z1.x + z2.x, qm = z1.y - z2.y;
        float qp = z1.y + z2.y, pm = z1.x - z2.x;
        Ia[j] = pr_ * pr_ + qm * qm;
        Ib[j] = qp * qp + pm * pm;
        psa += Ia[j]; psb += Ib[j];
    }
#pragma unroll
    for (int m = 1; m < 64; m <<= 1) {
        psa += __shfl_xor(psa, m); psb += __shfl_xor(psb, m);
    }
    if (psa == 0.f) psa = 1.f;
    if (psb == 0.f) psb = 1.f;
    const float inv_a = 1.f / psa, inv_b = 1.f / psb;
    __syncthreads();                    // all waves done reading Z

    float* myI = s_Iv + wv * 1152;      // row r at +r*288, idx f+(f>>3) (max 286)
#pragma unroll
    for (int j = 0; j < 4; j++) {
        int f = (l << 2) | j;
        int fi = f + (f >> 3);
        myI[fi] = Ia[j];
        myI[288 + fi] = Ib[j];
    }
    __syncthreads();

    // gate matmul, both rows: 16 experts x 4 lanes, 64 bins/lane
    {
        int e = l >> 2, cq = l & 3;
        float acc_a = 0.f, acc_b = 0.f;
#pragma unroll 4
        for (int j = 0; j < 64; j++) {
            int f = cq * 64 + j;
            int fi = f + (f >> 3);
            float wgv = WgT[f * 16 + e];
            acc_a += myI[fi] * wgv;
            acc_b += myI[288 + fi] * wgv;
        }
        acc_a += __shfl_xor(acc_a, 1); acc_a += __shfl_xor(acc_a, 2);
        acc_b += __shfl_xor(acc_b, 1); acc_b += __shfl_xor(acc_b, 2);
        if (cq == 0) {
            s_g[wv][0][e] = acc_a * inv_a + bgT[e];
            s_g[wv][1][e] = acc_b * inv_b + bgT[e];
        }
    }
    __syncthreads();

    // per-row: top-2, softmax, base output, record
#pragma unroll
    for (int r = 0; r < 2; r++) {
        const float mu = r ? mu_b : mu_a;
        const float sd = r ? sd_b : sd_a;
        const float last = r ? last_b : last_a;
        const int b = b0 + r;
        float b0v = -1e30f, b1v = -1e30f, b2v = -1e30f; int i0 = 0, i1 = 0;
        for (int i = 0; i < 16; i++) {
            float v = s_g[wv][r][i];
            if (v > b0v) { b2v = b1v; b1v = b0v; i1 = i0; b0v = v; i0 = i; }
            else if (v > b1v) { b2v = b1v; b1v = v; i1 = i; }
            else if (v > b2v) { b2v = v; }
        }
        float e1 = expf(b1v - b0v);
        float w0 = 1.f / (1.f + e1), w1 = e1 * w0;

        float* op = out + (size_t)b * NP;
        {
            int p = l;
            float v = 0.f; int ee = i0; float gw = w0;
#pragma unroll
            for (int k2 = 0; k2 < 2; k2++) {
                if (ee < NEL)       v += gw * (mu + br[ee * NP + p] * sd - mu * Ssum[ee * NP + p]);
                else if (ee == NEL) v += gw * mu;
                else                v += gw * last;
                ee = i1; gw = w1;
            }
            op[p] = v;
        }
        if (l < 32) {
            int p = 64 + l;
            float v = 0.f; int ee = i0; float gw = w0;
#pragma unroll
            for (int k2 = 0; k2 < 2; k2++) {
                if (ee < NEL)       v += gw * (mu + br[ee * NP + p] * sd - mu * Ssum[ee * NP + p]);
                else if (ee == NEL) v += gw * mu;
                else                v += gw * last;
                ee = i1; gw = w1;
            }
            op[p] = v;
        }
        if (l == 0) {
            rec[b] = make_int2(i0 | (i1 << 8), __float_as_int(w0));
            if (b1v - b2v < TAU) {
                int pos = atomicAdd(flagcnt, 1);
                flaglist[pos] = b;
            }
        }
    }
}

// f64 phasor-DFT refinement for flagged (near-tie) rows.
__global__ __launch_bounds__(256) void k_refine(
    const float* __restrict__ x, const double2* __restrict__ twd,
    const float* __restrict__ Wg, const float* __restrict__ bg,
    const float* __restrict__ Ssum, const float* __restrict__ br,
    float* __restrict__ out, int2* __restrict__ rec,
    const int* __restrict__ flaglist, const int* __restrict__ flagcnt)
{
    __shared__ double s_x[512];
    __shared__ double s_I[256];
    __shared__ double s_red[16];
    __shared__ double s_g[16];
    const int nf = *flagcnt;
    const int t = threadIdx.x;
    const int wid = t >> 6, lane = t & 63;
    for (int fi = blockIdx.x; fi < nf; fi += gridDim.x) {
        const int b = flaglist[fi];
        const float* xp = x + (size_t)b * NL;
        double v0 = (double)xp[t], v1 = (double)xp[t + 256];
        double lsum = v0 + v1, lsq = v0 * v0 + v1 * v1;
        for (int m = 1; m < 64; m <<= 1) { lsum += __shfl_xor(lsum, m); lsq += __shfl_xor(lsq, m); }
        if (lane == 0) { s_red[wid] = lsum; s_red[4 + wid] = lsq; }
        __syncthreads();
        double mu = (s_red[0] + s_red[1] + s_red[2] + s_red[3]) * (1.0 / 512.0);
        double var = (s_red[4] + s_red[5] + s_red[6] + s_red[7]) * (1.0 / 512.0) - mu * mu;
        double sd = sqrt(var + 1e-5);
        double last = (double)xp[511];
        s_x[t] = v0 - mu; s_x[t + 256] = v1 - mu;
        __syncthreads();
        double2 w = twd[t];
        double pr = 1.0, pi = 0.0, cr = 0.0, ci = 0.0;
        for (int n = 0; n < 512; n++) {
            double xv = s_x[n];
            cr += xv * pr; ci += xv * pi;
            double t2 = pr * w.x - pi * w.y;
            pi = pr * w.y + pi * w.x;
            pr = t2;
        }
        double I = cr * cr + ci * ci;
        s_I[t] = I;
        double ls = I;
        for (int m = 1; m < 64; m <<= 1) ls += __shfl_xor(ls, m);
        if (lane == 0) s_red[8 + wid] = ls;
        __syncthreads();
        double stot = s_red[8] + s_red[9] + s_red[10] + s_red[11];
        if (stot == 0.0) stot = 1.0;
        if (t < 16) {
            double acc = 0.0;
            const float* wrow = Wg + t * NF;
            for (int f = 0; f < NF; f++) acc += s_I[f] * (double)wrow[f];
            s_g[t] = (acc / stot + (double)bg[t]) * (1.0 / 0.07);
        }
        __syncthreads();
        if (t == 0) {
            double c0 = -1e300, c1 = -1e300; int j0 = 0, j1 = 0;
            for (int i = 0; i < 16; i++) {
                double v = s_g[i];
                if (v > c0) { c1 = c0; j1 = j0; c0 = v; j0 = i; }
                else if (v > c1) { c1 = v; j1 = i; }
            }
            double e1 = exp(c1 - c0);
            double w0 = 1.0 / (1.0 + e1);
            s_red[12] = w0;
            s_red[13] = (double)j0; s_red[14] = (double)j1;
        }
        __syncthreads();
        int i0 = (int)s_red[13], i1 = (int)s_red[14];
        float w0f = (float)s_red[12], w1f = 1.f - w0f;
        float muf = (float)mu, sdf = (float)sd, lastf = (float)last;
        if (t < NP) {
            float v = 0.f; int ee = i0; float gw = w0f;
            for (int k2 = 0; k2 < 2; k2++) {
                if (ee < NEL)       v += gw * (muf + br[ee * NP + t] * sdf - muf * Ssum[ee * NP + t]);
                else if (ee == NEL) v += gw * muf;
                else                v += gw * lastf;
                ee = i1; gw = w1f;
            }
            out[(size_t)b * NP + t] = v;
        }
        if (t == 0) rec[b] = make_int2(i0 | (i1 << 8), __float_as_int(w0f));
        __syncthreads();
    }
}

// Per-expert row lists from dense records; padded-line global atomics.
__global__ __launch_bounds__(256) void k_bucket(
    const int2* __restrict__ rec, int* __restrict__ cnt,
    int* __restrict__ idxl, float* __restrict__ wl)
{
    __shared__ int hcnt[16], hoff[16], hbase[16];
    const int t = threadIdx.x;
    const int b = blockIdx.x * 256 + t;
    int2 r = rec[b];
    int i0 = r.x & 0xff, i1 = (r.x >> 8) & 0xff;
    float w0 = __int_as_float(r.y), w1 = 1.f - w0;
    if (t < 16) { hcnt[t] = 0; hoff[t] = 0; }
    __syncthreads();
    if (i0 < NEL) atomicAdd(&hcnt[i0], 1);
    if (i1 < NEL) atomicAdd(&hcnt[i1], 1);
    __syncthreads();
    if (t < 16) hbase[t] = hcnt[t] ? atomicAdd(&cnt[t << 4], hcnt[t]) : 0;
    __syncthreads();
    if (i0 < NEL) {
        int p = hbase[i0] + atomicAdd(&hoff[i0], 1);
        idxl[(size_t)i0 * NB_B + p] = b;
        wl[(size_t)i0 * NB_B + p] = w0;
    }
    if (i1 < NEL) {
        int p = hbase[i1] + atomicAdd(&hoff[i1], 1);
        idxl[(size_t)i1 * NB_B + p] = b;
        wl[(size_t)i1 * NB_B + p] = w1;
    }
}

// Gathered per-expert MFMA GEMM: 64 rows x 96 cols x K=512 bf16.
#define NBCH 128
__global__ __launch_bounds__(256) void k_gemm(
    const float* __restrict__ x, const unsigned short* __restrict__ Wrb,
    float* __restrict__ out,
    const int* __restrict__ cnt, const int* __restrict__ idxl,
    const float* __restrict__ wl)
{
    __shared__ __align__(16) unsigned short sA[64 * 72];   // [r][k]
    __shared__ __align__(16) unsigned short sB[96 * 72];   // [p][k]
    __shared__ int   s_idx[64];
    __shared__ float s_w[64];
    const int e = blockIdx.x / NBCH;
    const int cb = blockIdx.x % NBCH;
    const int n = cnt[e << 4];
    const int nch = (n + 63) >> 6;
    const int t = threadIdx.x;
    const int lane = t & 63, wv = t >> 6;
    const int quad = lane >> 4, l16 = lane & 15;
    const int ar = t >> 2, asub = t & 3;
    const int* il = idxl + (size_t)e * NB_B;
    const float* wlp = wl + (size_t)e * NB_B;
    const unsigned short* wb = Wrb + (size_t)e * NP * NL;

    for (int cc = cb; cc < nch; cc += NBCH) {
        __syncthreads();
        if (t < 64) {
            int g = cc * 64 + t;
            bool vld = g < n;
            s_idx[t] = vld ? il[g] : il[0];
            s_w[t] = vld ? wlp[g] : 0.f;
        }
        __syncthreads();
        f32x4 acc[6];
#pragma unroll
        for (int j = 0; j < 6; j++) acc[j] = (f32x4){0.f, 0.f, 0.f, 0.f};
        const float* xrow = x + (size_t)s_idx[ar] * NL + asub * 16;

        for (int kb = 0; kb < NL; kb += 64) {
            {   // stage A: row ar, k in [kb+asub*16, +16), f32->bf16
                const float4* src = (const float4*)(xrow + kb);
                unsigned short tmp[16];
#pragma unroll
                for (int i = 0; i < 4; i++) {
                    float4 v = src[i];
                    tmp[i * 4 + 0] = f2bf(v.x); tmp[i * 4 + 1] = f2bf(v.y);
                    tmp[i * 4 + 2] = f2bf(v.z); tmp[i * 4 + 3] = f2bf(v.w);
                }
                unsigned short* dst = sA + ar * 72 + asub * 16;
                *(bf16x8*)dst       = *(bf16x8*)tmp;
                *(bf16x8*)(dst + 8) = *(bf16x8*)(tmp + 8);
            }
#pragma unroll
            for (int it = 0; it < 3; it++) {   // stage B: 96 p-rows x 64 k
                int f = t + it * 256;
                int p = f >> 3, kg = f & 7;
                bf16x8 v = *(const bf16x8*)(wb + (size_t)p * NL + kb + kg * 8);
                *(bf16x8*)(sB + p * 72 + kg * 8) = v;
            }
            __syncthreads();
#pragma unroll
            for (int ks = 0; ks < 2; ks++) {
                bf16x8 af = *(const bf16x8*)(sA + (wv * 16 + l16) * 72 + ks * 32 + quad * 8);
#pragma unroll
                for (int nt = 0; nt < 6; nt++) {
                    bf16x8 bf = *(const bf16x8*)(sB + (nt * 16 + l16) * 72 + ks * 32 + quad * 8);
                    acc[nt] = __builtin_amdgcn_mfma_f32_16x16x32_bf16(af, bf, acc[nt], 0, 0, 0);
                }
            }
            __syncthreads();
        }
#pragma unroll
        for (int i = 0; i < 4; i++) {
            int rloc = wv * 16 + quad * 4 + i;
            float wgt = s_w[rloc];
            float* orow = out + (size_t)s_idx[rloc] * NP;
#pragma unroll
            for (int nt = 0; nt < 6; nt++)
                unsafeAtomicAdd(&orow[nt * 16 + l16], wgt * acc[nt][i]);
        }
    }
}

extern "C" void kernel_launch(void* const* d_in, const int* in_sizes, int n_in,
                              void* d_out, int out_size, void* d_ws, size_t ws_size,
                              hipStream_t stream)
{
    const float* x  = (const float*)d_in[0];
    const float* Wg = (const float*)d_in[1];
    const float* bg = (const float*)d_in[2];
    const float* Wr = (const float*)d_in[3];
    const float* br = (const float*)d_in[4];
    float* out = (float*)d_out;
    char* ws = (char*)d_ws;

    int*     cnt      = (int*)(ws + WS_CNT);
    int*     flagcnt  = (int*)(ws + WS_FLAGCNT);
    float*   Ssum     = (float*)(ws + WS_SSUM);
    float*   WgT      = (float*)(ws + WS_WGT);
    float*   bgT      = (float*)(ws + WS_BGT);
    float2*  twf      = (float2*)(ws + WS_TWF);
    double2* twd      = (double2*)(ws + WS_TWD);
    int2*    rec      = (int2*)(ws + WS_REC);
    int*     idxl     = (int*)(ws + WS_IDXL);
    float*   wl       = (float*)(ws + WS_WL);
    unsigned short* Wrb = (unsigned short*)(ws + WS_WRB);
    int*     flaglist = idxl;   // overlay: consumed before k_bucket writes idxl

    k_prep<<<dim3(32), dim3(256), 0, stream>>>(Wg, bg, Wr, Ssum, WgT, bgT, twf, twd, cnt, flagcnt);
    k_cvt<<<dim3(672), dim3(256), 0, stream>>>((const float4*)Wr, (ushort4*)Wrb);
    k_gate<<<dim3(NB_B / 8), dim3(256), 0, stream>>>(x, WgT, bgT, twf, Ssum, br, out,
                                                     rec, flaglist, flagcnt);
    k_refine<<<dim3(512), dim3(256), 0, stream>>>(x, twd, Wg, bg, Ssum, br, out, rec,
                                                  flaglist, flagcnt);
    k_bucket<<<dim3(NB_B / 256), dim3(256), 0, stream>>>(rec, cnt, idxl, wl);
    k_gemm<<<dim3(NEL * NBCH), dim3(256), 0, stream>>>(x, Wrb, out, cnt, idxl, wl);
}